// Round 8
// baseline (602.610 us; speedup 1.0000x reference)
//
#include <hip/hip_runtime.h>

// y[n,m,:] = x[n,m,:] @ W[l(m)] * (1/sqrt(128))
// x: [100000, 16, 128] f32   W: [4, 128, 128] f32   y: [100000, 16, 128] f32
//
// R7 post-mortem: depth-2 neutral (309->311) -> in-block latency already
// TLP-covered; reverted to the R6 2-buffer schedule. At 5.3 TB/s combined
// (84% of the 6.29 TB/s mixed-copy ceiling) the remaining named mechanism is
// READ GRANULARITY: R6 blocks read 512B slices @ 8KB stride; a DRAM channel
// sees 512B chunks interleaved from 16 blocks. R8 (single variable): each
// block covers an m-PAIR -> tiles = 16 rows x 2 m, every stage instruction
// reads one contiguous 1KB row-chunk. Same tile bytes (16KB), same LDS
// (32KB, 4 blocks/CU), same per-phase budget (4 stage / 16 ds_read / 16
// MFMA / 4 stores per wave), same vmcnt schedule. W frags for both m in
// registers (64 VGPR, ~110 total < 128 cap @ launch_bounds(256,4)).
//
// Swizzle (rule #21 both-sides): stage row r is wave-uniform -> source slot
// = lane ^ (r&7) (16B slots), LDS dest linear; comp reads slot
// (mu*32+kk*8+lk*2+{0,1}) ^ (lr&7). Bank check: 8 lanes/bank-quad, 2/bank =
// free. MFMA: A=W-frag(d), B=x-frag(n=16 rows, fixed m), same
// k->(lanegroup,elem) map both sides (K-perm cancels). D: col(lane&15)=n,
// row((lane>>4)*4+reg)=d (HW-verified R1-R7).

typedef __bf16 bf16x8 __attribute__((ext_vector_type(8)));
typedef float f32x4 __attribute__((ext_vector_type(4)));
typedef unsigned short u16x8 __attribute__((ext_vector_type(8)));

#define N_NODES 100000
#define MCOMP 16
#define CIN 128
#define ROWSTRIDE (MCOMP * CIN)  // 2048 floats per node
#define TROWS 16                 // rows per tile (x 2 m = 16KB)

__device__ __forceinline__ unsigned short f2b(float f) {
    unsigned int u = __float_as_uint(f);
    unsigned int r = (u + 0x7fffu + ((u >> 16) & 1u)) >> 16;
    return (unsigned short)r;
}

// Wt[l][d][c] = W[l][c][d] * (1/sqrt(128)) as bf16 bits. 128 KiB in d_ws.
__global__ void prep_weights(const float* __restrict__ w,
                             unsigned short* __restrict__ wt) {
    int idx = blockIdx.x * blockDim.x + threadIdx.x;  // 0..65535
    int l = idx >> 14;
    int rem = idx & 16383;
    int d = rem >> 7;
    int c = rem & 127;
    const float pw = 0.08838834764831845f;  // 1/sqrt(128)
    wt[idx] = f2b(w[(l << 14) + (c << 7) + d] * pw);
}

__global__ __launch_bounds__(256, 4) void linear_mfma(
        const float* __restrict__ x,
        const unsigned short* __restrict__ wt,
        float* __restrict__ y) {
    __shared__ float lds0[TROWS * 256];  // 16 KiB: 16 rows x (2m x 128c)
    __shared__ float lds1[TROWS * 256];

    const int m0 = blockIdx.x * 2;     // m-pair fast dispatch dim
    const int wid = threadIdx.x >> 6;
    const int lane = threadIdx.x & 63;
    const int lr = lane & 15;   // W-frag d-row / x-frag n(row) / D col
    const int lk = lane >> 4;   // k lane-group
    const int nbase = blockIdx.y * (4 * TROWS);  // 64 rows per block

    // W fragments for both m of the pair, register-resident:
    // d = wid*32 + df*16 + lr, k = kk*32 + lk*8 .. +8
    bf16x8 wf[2][2][4];
#pragma unroll
    for (int mu = 0; mu < 2; ++mu) {
        int m = m0 + mu;
        int l = (m >= 9) ? 3 : (m >= 4) ? 2 : (m >= 1) ? 1 : 0;
        const unsigned short* wl = wt + (l << 14);
#pragma unroll
        for (int df = 0; df < 2; ++df)
#pragma unroll
            for (int kk = 0; kk < 4; ++kk)
                wf[mu][df][kk] = __builtin_bit_cast(bf16x8, *(const u16x8*)(
                    wl + (((wid * 32 + df * 16 + lr) << 7) + kk * 32 + lk * 8)));
    }

    // stage tile h (16 rows, both m): 4 instrs/wave, each one CONTIGUOUS 1KB
    // row-chunk. Wave-uniform row -> source slot = lane ^ (r&7), dest linear.
    auto stage = [&](float* buf, int h) {
        const int hbase = nbase + h * TROWS;
#pragma unroll
        for (int j = 0; j < 4; ++j) {
            int r = wid * 4 + j;                  // row 0..15, wave-uniform
            int slot = lane ^ (r & 7);            // 16B slot within 1KB chunk
            const float* src = x + (size_t)(hbase + r) * ROWSTRIDE
                               + m0 * CIN + slot * 4;
            __builtin_amdgcn_global_load_lds(
                (const __attribute__((address_space(1))) void*)src,
                (__attribute__((address_space(3))) void*)(buf + r * 256),
                16, 0, 0);
        }
    };

    // compute tile h: per wave 16 ds_read_b128, 16 MFMA, 4 dwordx4 stores.
    auto comp = [&](const float* buf, int h) {
        f32x4 acc[2][2];
#pragma unroll
        for (int mu = 0; mu < 2; ++mu)
#pragma unroll
            for (int df = 0; df < 2; ++df)
                acc[mu][df] = (f32x4){0.f, 0.f, 0.f, 0.f};

#pragma unroll
        for (int kk = 0; kk < 4; ++kk)
#pragma unroll
            for (int mu = 0; mu < 2; ++mu) {
                const int sw = lr & 7;
                const float* rbase = buf + lr * 256;
                int s0 = (mu * 32 + kk * 8 + lk * 2) ^ sw;
                int s1 = (mu * 32 + kk * 8 + lk * 2 + 1) ^ sw;
                f32x4 v0 = *(const f32x4*)(rbase + s0 * 4);
                f32x4 v1 = *(const f32x4*)(rbase + s1 * 4);
                bf16x8 xb;
#pragma unroll
                for (int jj = 0; jj < 4; ++jj) {
                    xb[jj] = (__bf16)v0[jj];
                    xb[jj + 4] = (__bf16)v1[jj];
                }
                acc[mu][0] = __builtin_amdgcn_mfma_f32_16x16x32_bf16(
                    wf[mu][0][kk], xb, acc[mu][0], 0, 0, 0);
                acc[mu][1] = __builtin_amdgcn_mfma_f32_16x16x32_bf16(
                    wf[mu][1][kk], xb, acc[mu][1], 0, 0, 0);
            }

        const int hbase = nbase + h * TROWS;
#pragma unroll
        for (int mu = 0; mu < 2; ++mu)
#pragma unroll
            for (int df = 0; df < 2; ++df) {
                float* yp = y + (size_t)(hbase + lr) * ROWSTRIDE
                            + (m0 + mu) * CIN + wid * 32 + df * 16 + lk * 4;
                *(f32x4*)yp = acc[mu][df];
            }
    };

    if (nbase + 4 * TROWS <= N_NODES) {
        // R6 schedule: stage(t+1); comp(t); vmcnt(4); barrier
        stage(lds0, 0);
        asm volatile("s_waitcnt vmcnt(0)" ::: "memory");
        __builtin_amdgcn_s_barrier();

        stage(lds1, 1);
        __builtin_amdgcn_sched_barrier(0);
        comp(lds0, 0);
        asm volatile("s_waitcnt vmcnt(4)" ::: "memory");
        __builtin_amdgcn_s_barrier();

        stage(lds0, 2);
        __builtin_amdgcn_sched_barrier(0);
        comp(lds1, 1);
        asm volatile("s_waitcnt vmcnt(4)" ::: "memory");
        __builtin_amdgcn_s_barrier();

        stage(lds1, 3);
        __builtin_amdgcn_sched_barrier(0);
        comp(lds0, 2);
        asm volatile("s_waitcnt vmcnt(4)" ::: "memory");
        __builtin_amdgcn_s_barrier();

        comp(lds1, 3);
    } else {
        // tail block: 100000 % 64 == 32 -> exactly 2 tiles
        stage(lds0, 0);
        stage(lds1, 1);
        asm volatile("s_waitcnt vmcnt(4)" ::: "memory");  // L0 done, L1 out
        __builtin_amdgcn_s_barrier();
        comp(lds0, 0);
        asm volatile("s_waitcnt vmcnt(4)" ::: "memory");  // L1 done, S0 out
        __builtin_amdgcn_s_barrier();
        comp(lds1, 1);
    }
}

extern "C" void kernel_launch(void* const* d_in, const int* in_sizes, int n_in,
                              void* d_out, int out_size, void* d_ws, size_t ws_size,
                              hipStream_t stream) {
    const float* x = (const float*)d_in[0];
    const float* w = (const float*)d_in[1];
    float* y = (float*)d_out;
    unsigned short* wt = (unsigned short*)d_ws;  // 128 KiB of scratch used

    prep_weights<<<256, 256, 0, stream>>>(w, wt);

    // m-pairs fast, node-tile slow: concurrent blocks cover all 16 m of
    // consecutive 64-row spans; every stage read is a contiguous 1KB chunk.
    dim3 grid(MCOMP / 2, (N_NODES + 4 * TROWS - 1) / (4 * TROWS));  // 8 x 1563
    linear_mfma<<<grid, 256, 0, stream>>>(x, wt, y);
}

// Round 9
// 479.911 us; speedup vs baseline: 1.2557x; 1.2557x over previous
//
#include <hip/hip_runtime.h>

// y[n,m,:] = x[n,m,:] @ W[l(m)] * (1/sqrt(128))
// x: [100000, 16, 128] f32   W: [4, 128, 128] f32   y: [100000, 16, 128] f32
//
// R8 post-mortem: m-pair tile spilled (VGPR_Count=64 vs ~100 live; SGPR=112;
// WRITE 2x = scratch traffic) -> 602us. Granularity theory untested, but any
// clean retest needs 64 VGPR of weights -- over budget. Reverted to R6.
// R9 isolates OCCUPANCY upward: 8 blocks/CU (launch_bounds(256,8), VGPR<=64)
// via 16-row tiles (two 8KB buffers, 16KB LDS). More independent per-CU
// request streams for DRAM scheduling; barrier stalls overlap across blocks.
// Per wave per tile: 2 stage loads, 8 ds_read, 8 MFMA, 2 stores; steady
// vmcnt(2) (outstanding = L(t)2 + S(t-1)2, wait leaves S(t-1)).
// VGPR budget: wf 32 + acc 8 + temps ~= 58 < 64.
//
// Unchanged from R6: m-fast grid (page locality win), global_load_lds w=16,
// rule #21 both-sides swizzle (source slot^=(row&7), linear DMA dest, XOR on
// ds_read), W register-resident. MFMA: A=W-frag(d), B=x-frag(n), same
// k->(lanegroup,elem) map both sides (K-perm cancels). D: col(lane&15)=n,
// row((lane>>4)*4+reg)=d (HW-verified R1-R8).

typedef __bf16 bf16x8 __attribute__((ext_vector_type(8)));
typedef float f32x4 __attribute__((ext_vector_type(4)));
typedef unsigned short u16x8 __attribute__((ext_vector_type(8)));

#define N_NODES 100000
#define MCOMP 16
#define CIN 128
#define ROWSTRIDE (MCOMP * CIN)  // 2048 floats per node
#define TROWS 16                 // rows per tile (8 KB)
#define TPB 8                    // tiles per block (128 rows)

__device__ __forceinline__ unsigned short f2b(float f) {
    unsigned int u = __float_as_uint(f);
    unsigned int r = (u + 0x7fffu + ((u >> 16) & 1u)) >> 16;
    return (unsigned short)r;
}

// Wt[l][d][c] = W[l][c][d] * (1/sqrt(128)) as bf16 bits. 128 KiB in d_ws.
__global__ void prep_weights(const float* __restrict__ w,
                             unsigned short* __restrict__ wt) {
    int idx = blockIdx.x * blockDim.x + threadIdx.x;  // 0..65535
    int l = idx >> 14;
    int rem = idx & 16383;
    int d = rem >> 7;
    int c = rem & 127;
    const float pw = 0.08838834764831845f;  // 1/sqrt(128)
    wt[idx] = f2b(w[(l << 14) + (c << 7) + d] * pw);
}

__global__ __launch_bounds__(256, 8) void linear_mfma(
        const float* __restrict__ x,
        const unsigned short* __restrict__ wt,
        float* __restrict__ y) {
    __shared__ float lds0[TROWS * 128];  // 8 KiB half-buffer A
    __shared__ float lds1[TROWS * 128];  // 8 KiB half-buffer B

    const int m = blockIdx.x;          // FAST dispatch dim (R6 win)
    const int l = (m >= 9) ? 3 : (m >= 4) ? 2 : (m >= 1) ? 1 : 0;
    const int wid = threadIdx.x >> 6;
    const int lane = threadIdx.x & 63;
    const int lr = lane & 15;   // W-frag d-row / x-frag n(row) / D col
    const int lk = lane >> 4;   // k lane-group
    const int nbase = blockIdx.y * (TROWS * TPB);  // 128 rows per block

    // W fragments, register-resident (32 VGPR):
    // d = wid*32 + df*16 + lr, k = kk*32 + lk*8 .. +8
    const unsigned short* wl = wt + (l << 14);
    bf16x8 wf[2][4];
#pragma unroll
    for (int df = 0; df < 2; ++df)
#pragma unroll
        for (int kk = 0; kk < 4; ++kk)
            wf[df][kk] = __builtin_bit_cast(bf16x8, *(const u16x8*)(
                wl + (((wid * 32 + df * 16 + lr) << 7) + kk * 32 + lk * 8)));

    // stage tile t (16 rows x 512B) into buf: 2 global_load_lds(16B)/wave.
    // LDS linear; global source pre-swizzled slot^=(row&7).
    auto stage = [&](float* buf, int t) {
        const int hbase = nbase + t * TROWS;
#pragma unroll
        for (int j = 0; j < 2; ++j) {
            int seg = wid * 2 + j;               // 1KB segment, wave-uniform
            int row = seg * 2 + (lane >> 5);     // 2 rows per segment
            int slot = (lane & 31) ^ (row & 7);  // 16B slot, pre-swizzled
            const float* src = x + (size_t)(hbase + row) * ROWSTRIDE
                               + m * CIN + slot * 4;
            __builtin_amdgcn_global_load_lds(
                (const __attribute__((address_space(1))) void*)src,
                (__attribute__((address_space(3))) void*)(buf + seg * 256),
                16, 0, 0);
        }
    };

    // compute tile t from buf: 8 ds_read_b128 (XOR-deswizzled), 8 MFMA,
    // 2 dwordx4 stores.
    auto comp = [&](const float* buf, int t) {
        f32x4 acc0 = (f32x4){0.f, 0.f, 0.f, 0.f};
        f32x4 acc1 = (f32x4){0.f, 0.f, 0.f, 0.f};
        const int sw = lr & 7;
        const float* rbase = buf + lr * 128;
#pragma unroll
        for (int kk = 0; kk < 4; ++kk) {
            f32x4 v0 = *(const f32x4*)(rbase + kk * 32 + ((lk * 2) ^ sw) * 4);
            f32x4 v1 = *(const f32x4*)(rbase + kk * 32 + ((lk * 2 + 1) ^ sw) * 4);
            bf16x8 xb;
#pragma unroll
            for (int jj = 0; jj < 4; ++jj) {
                xb[jj] = (__bf16)v0[jj];
                xb[jj + 4] = (__bf16)v1[jj];
            }
            acc0 = __builtin_amdgcn_mfma_f32_16x16x32_bf16(wf[0][kk], xb, acc0, 0, 0, 0);
            acc1 = __builtin_amdgcn_mfma_f32_16x16x32_bf16(wf[1][kk], xb, acc1, 0, 0, 0);
        }
        float* yp = y + (size_t)(nbase + t * TROWS + lr) * ROWSTRIDE + m * CIN
                    + wid * 32 + lk * 4;
        *(f32x4*)yp = acc0;
        *(f32x4*)(yp + 16) = acc1;
    };

    if (nbase + TROWS * TPB <= N_NODES) {
        // 2-buffer schedule, 8 tiles: stage(t+1); comp(t); vmcnt; barrier
        stage(lds0, 0);
        asm volatile("s_waitcnt vmcnt(0)" ::: "memory");
        __builtin_amdgcn_s_barrier();
#pragma unroll
        for (int t = 0; t < TPB; ++t) {
            if (t + 1 < TPB) stage((t & 1) ? lds0 : lds1, t + 1);
            __builtin_amdgcn_sched_barrier(0);
            comp((t & 1) ? lds1 : lds0, t);
            if (t + 1 < TPB) {
                // outstanding: L(t+1)=2 (issued first) + S(t)=2 -> wait to 2
                asm volatile("s_waitcnt vmcnt(2)" ::: "memory");
                __builtin_amdgcn_s_barrier();
            }
        }
    } else {
        // tail block: 100000 % 128 == 32 -> exactly 2 tiles
        stage(lds0, 0);
        stage(lds1, 1);
        asm volatile("s_waitcnt vmcnt(2)" ::: "memory");  // L0 done, L1 out
        __builtin_amdgcn_s_barrier();
        comp(lds0, 0);
        asm volatile("s_waitcnt vmcnt(2)" ::: "memory");  // L1 done, S0 out
        __builtin_amdgcn_s_barrier();
        comp(lds1, 1);
    }
}

extern "C" void kernel_launch(void* const* d_in, const int* in_sizes, int n_in,
                              void* d_out, int out_size, void* d_ws, size_t ws_size,
                              hipStream_t stream) {
    const float* x = (const float*)d_in[0];
    const float* w = (const float*)d_in[1];
    float* y = (float*)d_out;
    unsigned short* wt = (unsigned short*)d_ws;  // 128 KiB of scratch used

    prep_weights<<<256, 256, 0, stream>>>(w, wt);

    // m fast, node-tile slow (R6 win): one sequential HBM sweep.
    dim3 grid(MCOMP, (N_NODES + TROWS * TPB - 1) / (TROWS * TPB));  // 16 x 782
    linear_mfma<<<grid, 256, 0, stream>>>(x, wt, y);
}

// Round 10
// 305.281 us; speedup vs baseline: 1.9740x; 1.5720x over previous
//
#include <hip/hip_runtime.h>

// y[n,m,:] = x[n,m,:] @ W[l(m)] * (1/sqrt(128))
// x: [100000, 16, 128] f32   W: [4, 128, 128] f32   y: [100000, 16, 128] f32
//
// R9 post-mortem: occupancy-8 test confounded (VGPR capped at 32 -> weights
// not register-resident, +373MB re-fetch). R8's granularity test confounded
// (spill at 64-cap). R10 retests GRANULARITY with the register budget
// respected: 512-thread blocks over an m-PAIR; waves 0-3 own m0, waves 4-7
// own m1, each wave a 32-wide d-slice -> weights stay 32 VGPR/wave (R6
// budget). Tile = 32 rows x 2 m = 32KB; every stage instruction = one wave
// reading one CONTIGUOUS 1KB row-chunk (vs R6's 512B half-wave @ 8KB
// stride). Two buffers = 64KB LDS -> 2 blocks/CU = 16 waves/CU (same wave
// count as R6; only granularity changes). Same schedule + vmcnt counts
// (4 loads, 4 stores per wave per tile -> steady vmcnt(4)).
//
// Swizzle (rule #21): stage row r wave-uniform, source slot = lane ^ (r&7)
// (16B slots, XOR stays within each m's 512B half), LDS dest linear; comp
// reads slot (kk*8 + lk*2 + j) ^ (lr&7) within half mu*512B. Bank: 2-way
// b128 minimum (free). MFMA: A=W-frag(d), B=x-frag(n), same
// k->(lanegroup,elem) map both sides (K-perm cancels). D: col(lane&15)=n,
// row((lane>>4)*4+reg)=d (HW-verified R1-R9).

typedef __bf16 bf16x8 __attribute__((ext_vector_type(8)));
typedef float f32x4 __attribute__((ext_vector_type(4)));
typedef unsigned short u16x8 __attribute__((ext_vector_type(8)));

#define N_NODES 100000
#define MCOMP 16
#define CIN 128
#define ROWSTRIDE (MCOMP * CIN)  // 2048 floats per node
#define TROWS 32                 // rows per tile (x 2 m = 32 KB)
#define TPB 4                    // tiles per block (128 rows)

__device__ __forceinline__ unsigned short f2b(float f) {
    unsigned int u = __float_as_uint(f);
    unsigned int r = (u + 0x7fffu + ((u >> 16) & 1u)) >> 16;
    return (unsigned short)r;
}

// Wt[l][d][c] = W[l][c][d] * (1/sqrt(128)) as bf16 bits. 128 KiB in d_ws.
__global__ void prep_weights(const float* __restrict__ w,
                             unsigned short* __restrict__ wt) {
    int idx = blockIdx.x * blockDim.x + threadIdx.x;  // 0..65535
    int l = idx >> 14;
    int rem = idx & 16383;
    int d = rem >> 7;
    int c = rem & 127;
    const float pw = 0.08838834764831845f;  // 1/sqrt(128)
    wt[idx] = f2b(w[(l << 14) + (c << 7) + d] * pw);
}

__global__ __launch_bounds__(512, 4) void linear_mfma(
        const float* __restrict__ x,
        const unsigned short* __restrict__ wt,
        float* __restrict__ y) {
    __shared__ float lds0[TROWS * 256];  // 32 KiB: 32 rows x (2m x 128c)
    __shared__ float lds1[TROWS * 256];

    const int m0 = blockIdx.x * 2;      // m-pair, FAST dispatch dim
    const int wid = threadIdx.x >> 6;   // 0..7
    const int mu = wid >> 2;            // 0: m0, 1: m0+1
    const int wq = wid & 3;             // d-slice [wq*32, +32) within its m
    const int lane = threadIdx.x & 63;
    const int lr = lane & 15;   // W-frag d-row / x-frag n(row) / D col
    const int lk = lane >> 4;   // k lane-group
    const int nbase = blockIdx.y * (TROWS * TPB);  // 128 rows per block

    const int m = m0 + mu;
    const int l = (m >= 9) ? 3 : (m >= 4) ? 2 : (m >= 1) ? 1 : 0;

    // W fragments, register-resident (32 VGPR):
    // d = wq*32 + df*16 + lr, k = kk*32 + lk*8 .. +8
    const unsigned short* wl = wt + (l << 14);
    bf16x8 wf[2][4];
#pragma unroll
    for (int df = 0; df < 2; ++df)
#pragma unroll
        for (int kk = 0; kk < 4; ++kk)
            wf[df][kk] = __builtin_bit_cast(bf16x8, *(const u16x8*)(
                wl + (((wq * 32 + df * 16 + lr) << 7) + kk * 32 + lk * 8)));

    // stage tile t: 32 rows x 1KB (both m). 4 instrs/wave; each instruction
    // = one wave reading one CONTIGUOUS 1KB row-chunk. Source slot pre-
    // swizzled lane^(r&7) (within-half XOR), LDS dest linear.
    auto stage = [&](float* buf, int t) {
        const int hbase = nbase + t * TROWS;
#pragma unroll
        for (int j = 0; j < 4; ++j) {
            int r = wid * 4 + j;                 // row 0..31, wave-uniform
            int slot = lane ^ (r & 7);           // 16B slot within 1KB row
            const float* src = x + (size_t)(hbase + r) * ROWSTRIDE
                               + m0 * CIN + slot * 4;
            __builtin_amdgcn_global_load_lds(
                (const __attribute__((address_space(1))) void*)src,
                (__attribute__((address_space(3))) void*)(buf + r * 256),
                16, 0, 0);
        }
    };

    // compute tile t: per wave 8 ds_read_b128 (deswizzled), 16 MFMA, 4 stores.
    auto comp = [&](const float* buf, int t) {
        f32x4 acc[2][2];
#pragma unroll
        for (int rf = 0; rf < 2; ++rf)
#pragma unroll
            for (int df = 0; df < 2; ++df)
                acc[rf][df] = (f32x4){0.f, 0.f, 0.f, 0.f};

#pragma unroll
        for (int kk = 0; kk < 4; ++kk)
#pragma unroll
            for (int rf = 0; rf < 2; ++rf) {
                int row = rf * 16 + lr;
                int sw = row & 7;
                const float* rbase = buf + row * 256 + mu * 128 + kk * 32;
                f32x4 v0 = *(const f32x4*)(rbase + ((lk * 2) ^ sw) * 4);
                f32x4 v1 = *(const f32x4*)(rbase + ((lk * 2 + 1) ^ sw) * 4);
                bf16x8 xb;
#pragma unroll
                for (int jj = 0; jj < 4; ++jj) {
                    xb[jj] = (__bf16)v0[jj];
                    xb[jj + 4] = (__bf16)v1[jj];
                }
                acc[rf][0] = __builtin_amdgcn_mfma_f32_16x16x32_bf16(
                    wf[0][kk], xb, acc[rf][0], 0, 0, 0);
                acc[rf][1] = __builtin_amdgcn_mfma_f32_16x16x32_bf16(
                    wf[1][kk], xb, acc[rf][1], 0, 0, 0);
            }

        const int hbase = nbase + t * TROWS;
#pragma unroll
        for (int rf = 0; rf < 2; ++rf)
#pragma unroll
            for (int df = 0; df < 2; ++df) {
                float* yp = y + (size_t)(hbase + rf * 16 + lr) * ROWSTRIDE
                            + m * CIN + wq * 32 + df * 16 + lk * 4;
                *(f32x4*)yp = acc[rf][df];
            }
    };

    if (nbase + TROWS * TPB <= N_NODES) {
        // R6 schedule, 4 tiles: per wave 4 loads + 4 stores per iter.
        stage(lds0, 0);
        asm volatile("s_waitcnt vmcnt(0)" ::: "memory");
        __builtin_amdgcn_s_barrier();

        stage(lds1, 1);
        __builtin_amdgcn_sched_barrier(0);
        comp(lds0, 0);
        asm volatile("s_waitcnt vmcnt(4)" ::: "memory");  // L1 done, S0 out
        __builtin_amdgcn_s_barrier();

        stage(lds0, 2);
        __builtin_amdgcn_sched_barrier(0);
        comp(lds1, 1);
        asm volatile("s_waitcnt vmcnt(4)" ::: "memory");
        __builtin_amdgcn_s_barrier();

        stage(lds1, 3);
        __builtin_amdgcn_sched_barrier(0);
        comp(lds0, 2);
        asm volatile("s_waitcnt vmcnt(4)" ::: "memory");
        __builtin_amdgcn_s_barrier();

        comp(lds1, 3);
    } else {
        // tail block: 100000 % 128 == 32 -> exactly 1 tile
        stage(lds0, 0);
        asm volatile("s_waitcnt vmcnt(0)" ::: "memory");
        __builtin_amdgcn_s_barrier();
        comp(lds0, 0);
    }
}

extern "C" void kernel_launch(void* const* d_in, const int* in_sizes, int n_in,
                              void* d_out, int out_size, void* d_ws, size_t ws_size,
                              hipStream_t stream) {
    const float* x = (const float*)d_in[0];
    const float* w = (const float*)d_in[1];
    float* y = (float*)d_out;
    unsigned short* wt = (unsigned short*)d_ws;  // 128 KiB of scratch used

    prep_weights<<<256, 256, 0, stream>>>(w, wt);

    // m-pairs fast, node-tile slow: concurrent blocks cover all 16 m of
    // consecutive 128-row spans; every stage read is a contiguous 1KB chunk.
    dim3 grid(MCOMP / 2, (N_NODES + TROWS * TPB - 1) / (TROWS * TPB));  // 8x782
    linear_mfma<<<grid, 512, 0, stream>>>(x, wt, y);
}